// Round 12
// baseline (169.051 us; speedup 1.0000x reference)
//
#include <hip/hip_runtime.h>
#include <hip/hip_fp16.h>
#include <math.h>

#define N_IN_CH 256
#define N_OUT   256   // HEADS * OUT_CH
#define HEADS   4
#define OUT_CH  64
#define BM      32    // M-tile: 16KB LDS, 32 AGPR -> ~5 blocks/CU (vs 2 at BM=64)
#define SCAN_BLOCK 1024

typedef __attribute__((ext_vector_type(8))) short bf16x8;
typedef __attribute__((ext_vector_type(4))) float f32x4;

__device__ __forceinline__ float lrelu(float a) {
  return a >= 0.f ? a : 0.2f * a;
}

__device__ __forceinline__ ushort f2bf(float f) {
  uint u = __float_as_uint(f);
  uint r = (u + 0x7FFFu + ((u >> 16) & 1u)) >> 16;
  return (ushort)r;
}

__device__ __forceinline__ ushort f2h(float f) {
  return __half_as_ushort(__float2half(f));
}
__device__ __forceinline__ float h2f(ushort u) {
  return __half2float(__ushort_as_half(u));
}

// wave-level exclusive scan of partials[0..nparts) -> per-lane excl value
__device__ __forceinline__ int wave_scan_partials(const int* __restrict__ partials,
                                                  int nparts, int lane) {
  int pv = (lane < nparts) ? partials[lane] : 0;
  int incl = pv;
#pragma unroll
  for (int d = 1; d < 64; d <<= 1) {
    int t = __shfl_up(incl, d, 64);
    if (lane >= d) incl += t;
  }
  return incl - pv;
}

// -------- Kernel W: weight [H][K][C] fp32 -> Bt [N][K] bf16; zero counts ----
__global__ void convert_w(const float* __restrict__ w, ushort* __restrict__ bt,
                          int* __restrict__ counts, int nnodes) {
  const int idx = blockIdx.x * 256 + threadIdx.x;  // 0..65535
  if (idx < nnodes) counts[idx] = 0;
  const int n = idx >> 8, k = idx & 255;
  const int h = n >> 6, c = n & 63;
  bt[idx] = f2bf(w[h * (N_IN_CH * OUT_CH) + k * OUT_CH + c]);
}

// ------- Kernel B: count edges per destination + per-edge rank (1/thread) ---
// STANDALONE on purpose (twice-confirmed): fusing this with proj (R4 serial
// tail, R11 heterogeneous blocks) drags it to proj's 25% occupancy and costs
// 35-65 us. Alone: 20 VGPR, no LDS, full occupancy.
__global__ void count_kernel(const int* __restrict__ row, int* __restrict__ counts,
                             int* __restrict__ rank, int nedges) {
  int e = blockIdx.x * blockDim.x + threadIdx.x;
  if (e < nedges) rank[e] = atomicAdd(&counts[row[e]], 1);
}

// -------- Kernel A: x_h = x @ W' via MFMA + fused attention logits ----------
// BM=32: block = 4 waves; wave w owns head w (64 cols) x 32 rows.
__global__ __launch_bounds__(256) void proj_mfma(
    const float* __restrict__ x, const ushort* __restrict__ bt,
    const float* __restrict__ att_src, const float* __restrict__ att_dst,
    ushort* __restrict__ xh, float* __restrict__ asrc, float* __restrict__ adst,
    int nnodes) {
  __shared__ ushort at[BM * N_IN_CH];  // 16 KB, XOR-swizzled rows of A (bf16)
  const int tid = threadIdx.x;
  const int wave = tid >> 6;
  const int lane = tid & 63;
  const int n0 = blockIdx.x * BM;

  // ---- stage A: fp32 -> bf16, swizzled LDS write (conflict-free) ----
  {
    const int rsub = tid >> 6;        // 0..3
    const int cf = (tid & 63) * 4;    // float col
    const int cb = cf * 2;            // byte col
#pragma unroll
    for (int it = 0; it < 8; ++it) {
      const int row_ = it * 4 + rsub;
      const int grow = n0 + row_;
      float4 xv = make_float4(0.f, 0.f, 0.f, 0.f);
      if (grow < nnodes) xv = *(const float4*)&x[(size_t)grow * N_IN_CH + cf];
      ushort4 b;
      b.x = f2bf(xv.x); b.y = f2bf(xv.y); b.z = f2bf(xv.z); b.w = f2bf(xv.w);
      const int cbs = cb ^ ((row_ & 7) << 4);
      *(ushort4*)((char*)at + row_ * 512 + cbs) = b;
    }
  }
  __syncthreads();

  f32x4 acc[2][4];
#pragma unroll
  for (int mt = 0; mt < 2; ++mt)
#pragma unroll
    for (int nt = 0; nt < 4; ++nt) acc[mt][nt] = (f32x4){0.f, 0.f, 0.f, 0.f};

  const int lmod = lane & 15;
  const int ldiv = lane >> 4;

  for (int ks = 0; ks < 8; ++ks) {
    bf16x8 a[2], b[4];
#pragma unroll
    for (int mt = 0; mt < 2; ++mt) {
      const int row_ = mt * 16 + lmod;
      const int kb = ks * 64 + ldiv * 16;
      const int cbs = kb ^ ((row_ & 7) << 4);
      a[mt] = *(const bf16x8*)((const char*)at + row_ * 512 + cbs);
    }
#pragma unroll
    for (int nt = 0; nt < 4; ++nt) {
      const int n = wave * 64 + nt * 16 + lmod;
      b[nt] = *(const bf16x8*)&bt[(size_t)n * N_IN_CH + ks * 32 + ldiv * 8];
    }
#pragma unroll
    for (int mt = 0; mt < 2; ++mt)
#pragma unroll
      for (int nt = 0; nt < 4; ++nt)
        acc[mt][nt] = __builtin_amdgcn_mfma_f32_16x16x32_bf16(
            a[mt], b[nt], acc[mt][nt], 0, 0, 0);
  }

  float atts[4], attd[4];
#pragma unroll
  for (int nt = 0; nt < 4; ++nt) {
    const int gcol = wave * 64 + nt * 16 + lmod;
    atts[nt] = att_src[gcol];
    attd[nt] = att_dst[gcol];
  }

#pragma unroll
  for (int mt = 0; mt < 2; ++mt) {
#pragma unroll
    for (int reg = 0; reg < 4; ++reg) {
      const int grow = n0 + mt * 16 + ldiv * 4 + reg;  // C/D: row=(lane>>4)*4+reg
      const bool ok = grow < nnodes;
      float vs = 0.f, vd = 0.f;
#pragma unroll
      for (int nt = 0; nt < 4; ++nt) {
        const float v = acc[mt][nt][reg];
        if (ok) xh[(size_t)grow * N_OUT + wave * 64 + nt * 16 + lmod] = f2h(v);
        vs = fmaf(v, atts[nt], vs);
        vd = fmaf(v, attd[nt], vd);
      }
#pragma unroll
      for (int d = 1; d < 16; d <<= 1) {
        vs += __shfl_xor(vs, d, 64);
        vd += __shfl_xor(vd, d, 64);
      }
      if (lmod == 0 && ok) {
        asrc[grow * HEADS + wave] = vs;
        adst[grow * HEADS + wave] = vd;
      }
    }
  }
}

// ---------------- scan1: block-local exclusive scan over n+1 elems ----------
__global__ __launch_bounds__(SCAN_BLOCK) void scan1_kernel(
    const int* __restrict__ counts, int* __restrict__ offsets,
    int* __restrict__ partials, int n) {
  __shared__ int wsum[16];
  const int tid = threadIdx.x;
  const int lane = tid & 63;
  const int wid = tid >> 6;
  const int i = blockIdx.x * SCAN_BLOCK + tid;
  int v = (i < n) ? counts[i] : 0;
  int incl = v;
#pragma unroll
  for (int d = 1; d < 64; d <<= 1) {
    int t = __shfl_up(incl, d, 64);
    if (lane >= d) incl += t;
  }
  if (lane == 63) wsum[wid] = incl;
  __syncthreads();
  if (wid == 0) {
    int wv = (lane < 16) ? wsum[lane] : 0;
#pragma unroll
    for (int d = 1; d < 16; d <<= 1) {
      int t = __shfl_up(wv, d, 64);
      if (lane >= d) wv += t;
    }
    if (lane < 16) wsum[lane] = wv;
  }
  __syncthreads();
  const int wexcl = (wid == 0) ? 0 : wsum[wid - 1];
  if (i <= n) offsets[i] = wexcl + incl - v;
  if (tid == SCAN_BLOCK - 1) partials[blockIdx.x] = wsum[15];
}

// -- scatter: packed 16B edge record {col, 4xf16 weights}; inline scan2 ------
__global__ void scatter_kernel(const int* __restrict__ row, const int* __restrict__ col,
                               const int* __restrict__ rank,
                               const int* __restrict__ offsets,
                               const int* __restrict__ partials, int nparts,
                               const float* __restrict__ asrc,
                               const float* __restrict__ adst,
                               uint4* __restrict__ erec, int nedges) {
  const int lane = threadIdx.x & 63;
  const int excl = wave_scan_partials(partials, nparts, lane);
  int e = blockIdx.x * blockDim.x + threadIdx.x;
  if (e < nedges) {
    const int r = row[e];
    const int c = col[e];
    const int pos = offsets[r] + __shfl(excl, r >> 10, 64) + rank[e];
    const float4 s = *(const float4*)&asrc[r * 4];
    const float4 d = *(const float4*)&adst[c * 4];
    uint4 rec;
    rec.x = (uint)c;
    rec.y = (uint)f2h(__expf(lrelu(s.x + d.x))) |
            ((uint)f2h(__expf(lrelu(s.y + d.y))) << 16);
    rec.z = (uint)f2h(__expf(lrelu(s.z + d.z))) |
            ((uint)f2h(__expf(lrelu(s.w + d.w))) << 16);
    rec.w = 0u;
    erec[pos] = rec;
  }
}

// ------- gather: coalesced edge records + shuffle-addressed xh pipeline -----
__global__ __launch_bounds__(256) void gather_kernel(
    const int* __restrict__ offsets,
    const int* __restrict__ partials, int nparts,
    const uint4* __restrict__ erec,
    const ushort* __restrict__ xh, const float* __restrict__ bias,
    float* __restrict__ out, int nnodes) {
  __shared__ float pbuf[4][64 * 4];
  const int wv = threadIdx.x >> 6;
  const int lane = threadIdx.x & 63;
  const int n = blockIdx.x * 4 + wv;
  if (n >= nnodes) return;
  const int excl = wave_scan_partials(partials, nparts, lane);
  const int off = offsets[n] + __shfl(excl, n >> 10, 64);
  const int end = offsets[n + 1] + __shfl(excl, (n + 1) >> 10, 64);
  const int deg = end - off;
  const int half = lane >> 5;        // 0: even edges, 1: odd edges
  const int ch8 = (lane & 31) * 8;   // this lane's 8 output channels
  const int hh = (lane & 31) >> 3;   // head owning those channels

  float4 s4 = make_float4(0.f, 0.f, 0.f, 0.f);
  float a0 = 0.f, a1 = 0.f, a2 = 0.f, a3 = 0.f;
  float a4 = 0.f, a5 = 0.f, a6 = 0.f, a7 = 0.f;

  for (int b = 0; b < deg; b += 64) {
    const int cnt = min(64, deg - b);
    // one coalesced 16B load: source id + 4 precomputed f16 weights
    int cl_l = 0;
    float4 p = make_float4(0.f, 0.f, 0.f, 0.f);
    if (lane < cnt) {
      const uint4 rec = erec[off + b + lane];
      cl_l = (int)rec.x;
      p.x = h2f((ushort)(rec.y & 0xFFFFu));
      p.y = h2f((ushort)(rec.y >> 16));
      p.z = h2f((ushort)(rec.z & 0xFFFFu));
      p.w = h2f((ushort)(rec.z >> 16));
      s4.x += p.x; s4.y += p.y; s4.z += p.z; s4.w += p.w;
    }
    *(float4*)&pbuf[wv][lane * 4] = p;
    // same-wave LDS write->read ordered via lgkmcnt (no barrier needed)

    for (int j = 0; j < cnt; j += 16) {
      // distribute addresses via shuffles, issue payload loads immediately.
      // invalid tail slots carry cl=0 (safe read) and weight 0.
      int cq[8];
#pragma unroll
      for (int q = 0; q < 8; ++q) cq[q] = __shfl(cl_l, j + 2 * q + half, 64);
      uint4 xq[8];
#pragma unroll
      for (int q = 0; q < 8; ++q)
        xq[q] = *(const uint4*)&xh[(size_t)cq[q] * N_OUT + ch8];

      float wq[8];
#pragma unroll
      for (int q = 0; q < 8; ++q) wq[q] = pbuf[wv][(j + 2 * q + half) * 4 + hh];

#pragma unroll
      for (int q = 0; q < 8; ++q) {
        a0 = fmaf(wq[q], h2f((ushort)(xq[q].x & 0xFFFFu)), a0);
        a1 = fmaf(wq[q], h2f((ushort)(xq[q].x >> 16)), a1);
        a2 = fmaf(wq[q], h2f((ushort)(xq[q].y & 0xFFFFu)), a2);
        a3 = fmaf(wq[q], h2f((ushort)(xq[q].y >> 16)), a3);
        a4 = fmaf(wq[q], h2f((ushort)(xq[q].z & 0xFFFFu)), a4);
        a5 = fmaf(wq[q], h2f((ushort)(xq[q].z >> 16)), a5);
        a6 = fmaf(wq[q], h2f((ushort)(xq[q].w & 0xFFFFu)), a6);
        a7 = fmaf(wq[q], h2f((ushort)(xq[q].w >> 16)), a7);
      }
    }
  }

  // combine the two edge-halves (both halves end with the full sum)
  a0 += __shfl_xor(a0, 32, 64);
  a1 += __shfl_xor(a1, 32, 64);
  a2 += __shfl_xor(a2, 32, 64);
  a3 += __shfl_xor(a3, 32, 64);
  a4 += __shfl_xor(a4, 32, 64);
  a5 += __shfl_xor(a5, 32, 64);
  a6 += __shfl_xor(a6, 32, 64);
  a7 += __shfl_xor(a7, 32, 64);

  // reduce softmax denominators across all lanes
#pragma unroll
  for (int d = 1; d < 64; d <<= 1) {
    s4.x += __shfl_xor(s4.x, d, 64);
    s4.y += __shfl_xor(s4.y, d, 64);
    s4.z += __shfl_xor(s4.z, d, 64);
    s4.w += __shfl_xor(s4.w, d, 64);
  }
  const float sh = (hh == 0) ? s4.x : (hh == 1) ? s4.y : (hh == 2) ? s4.z : s4.w;
  const float invh = 1.f / fmaxf(sh, 1e-16f);

  // each half writes 4 of the lane's 8 channels (fully coalesced 256 floats)
  const int wch = ch8 + half * 4;
  const float4 b4 = *(const float4*)&bias[wch];
  float4 o;
  o.x = fmaf(half ? a4 : a0, invh, b4.x);
  o.y = fmaf(half ? a5 : a1, invh, b4.y);
  o.z = fmaf(half ? a6 : a2, invh, b4.z);
  o.w = fmaf(half ? a7 : a3, invh, b4.w);
  *(float4*)&out[(size_t)n * N_OUT + wch] = o;
}

extern "C" void kernel_launch(void* const* d_in, const int* in_sizes, int n_in,
                              void* d_out, int out_size, void* d_ws, size_t ws_size,
                              hipStream_t stream) {
  const float* x        = (const float*)d_in[0];
  const int*   edge_idx = (const int*)d_in[1];
  const float* weight   = (const float*)d_in[2];
  const float* att_src  = (const float*)d_in[3];
  const float* att_dst  = (const float*)d_in[4];
  const float* bias     = (const float*)d_in[5];
  float* out = (float*)d_out;

  const int nnodes = in_sizes[0] / N_IN_CH;
  const int nedges = in_sizes[1] / 2;
  const int* row = edge_idx;            // destinations (segment index)
  const int* col = edge_idx + nedges;   // sources (features gathered)

  char* wsb = (char*)d_ws;
  size_t woff = 0;
  auto alloc = [&](size_t bytes) -> char* {
    char* p = wsb + woff;
    woff += (bytes + 255) & ~(size_t)255;
    return p;
  };
  ushort* xh    = (ushort*)alloc((size_t)nnodes * N_OUT * sizeof(ushort));
  ushort* bt    = (ushort*)alloc((size_t)N_OUT * N_IN_CH * sizeof(ushort));
  float* asrc   = (float*)alloc((size_t)nnodes * HEADS * sizeof(float));
  float* adst   = (float*)alloc((size_t)nnodes * HEADS * sizeof(float));
  int* counts   = (int*)alloc((size_t)nnodes * sizeof(int));
  int* offsets  = (int*)alloc((size_t)(nnodes + 1) * sizeof(int));
  int* partials = (int*)alloc(256 * sizeof(int));
  int* rank     = (int*)alloc((size_t)nedges * sizeof(int));
  uint4* erec   = (uint4*)alloc((size_t)nedges * sizeof(uint4));

  convert_w<<<256, 256, 0, stream>>>(weight, bt, counts, nnodes);

  const int eblocks = (nedges + 255) / 256;
  count_kernel<<<eblocks, 256, 0, stream>>>(row, counts, rank, nedges);

  const int nblocksA = (nnodes + BM - 1) / BM;
  proj_mfma<<<nblocksA, 256, 0, stream>>>(x, bt, att_src, att_dst,
                                          xh, asrc, adst, nnodes);

  const int nscan = (nnodes + 1 + SCAN_BLOCK - 1) / SCAN_BLOCK;  // 49
  scan1_kernel<<<nscan, SCAN_BLOCK, 0, stream>>>(counts, offsets, partials, nnodes);

  scatter_kernel<<<eblocks, 256, 0, stream>>>(row, col, rank, offsets,
                                              partials, nscan,
                                              asrc, adst, erec, nedges);

  gather_kernel<<<(nnodes + 3) / 4, 256, 0, stream>>>(offsets, partials, nscan,
                                                      erec, xh, bias, out, nnodes);
}

// Round 13
// 165.905 us; speedup vs baseline: 1.0190x; 1.0190x over previous
//
#include <hip/hip_runtime.h>
#include <hip/hip_fp16.h>
#include <math.h>

#define N_IN_CH 256
#define N_OUT   256   // HEADS * OUT_CH
#define HEADS   4
#define OUT_CH  64
#define BM      64    // M-tile (BM=32 regressed: doubles per-row B traffic, R12)
#define SCAN_ELEMS 1024   // elements per scan block (256 threads x 4)

typedef __attribute__((ext_vector_type(8))) short bf16x8;
typedef __attribute__((ext_vector_type(4))) float f32x4;

__device__ __forceinline__ float lrelu(float a) {
  return a >= 0.f ? a : 0.2f * a;
}

__device__ __forceinline__ ushort f2bf(float f) {
  uint u = __float_as_uint(f);
  uint r = (u + 0x7FFFu + ((u >> 16) & 1u)) >> 16;
  return (ushort)r;
}

__device__ __forceinline__ ushort f2h(float f) {
  return __half_as_ushort(__float2half(f));
}
__device__ __forceinline__ float h2f(ushort u) {
  return __half2float(__ushort_as_half(u));
}

// wave-level exclusive scan of partials[0..nparts) -> per-lane excl value
__device__ __forceinline__ int wave_scan_partials(const int* __restrict__ partials,
                                                  int nparts, int lane) {
  int pv = (lane < nparts) ? partials[lane] : 0;
  int incl = pv;
#pragma unroll
  for (int d = 1; d < 64; d <<= 1) {
    int t = __shfl_up(incl, d, 64);
    if (lane >= d) incl += t;
  }
  return incl - pv;
}

// -------- Kernel W: weight [H][K][C] fp32 -> Bt [N][K] bf16; zero counts ----
__global__ void convert_w(const float* __restrict__ w, ushort* __restrict__ bt,
                          int* __restrict__ counts, int nnodes) {
  const int idx = blockIdx.x * 256 + threadIdx.x;  // 0..65535
  if (idx < nnodes) counts[idx] = 0;
  const int n = idx >> 8, k = idx & 255;
  const int h = n >> 6, c = n & 63;
  bt[idx] = f2bf(w[h * (N_IN_CH * OUT_CH) + k * OUT_CH + c]);
}

// ------- Kernel B: count edges per destination + per-edge rank (1/thread) ---
// STANDALONE (twice-confirmed: any fusion with proj's footprint costs 35-65us)
__global__ void count_kernel(const int* __restrict__ row, int* __restrict__ counts,
                             int* __restrict__ rank, int nedges) {
  int e = blockIdx.x * blockDim.x + threadIdx.x;
  if (e < nedges) rank[e] = atomicAdd(&counts[row[e]], 1);
}

// ---- Kernel A: proj (blocks [0,nblocksA)) || scan1 (tail blocks) -----------
// scan1 rides along the proj launch: tiny (49 blocks), runs concurrently with
// proj's 782 MFMA blocks -> saves a dispatch with no serial-path penalty.
// (Different from the failed count fusions: scan1 has no latency-sensitive
// 800k-atomic loop; it's ~2us of coalesced work.)
__global__ __launch_bounds__(256) void proj_scan(
    const float* __restrict__ x, const ushort* __restrict__ bt,
    const float* __restrict__ att_src, const float* __restrict__ att_dst,
    ushort* __restrict__ xh, float* __restrict__ asrc, float* __restrict__ adst,
    int nnodes, int nblocksA,
    const int* __restrict__ counts, int* __restrict__ offsets,
    int* __restrict__ partials) {
  __shared__ ushort at[BM * N_IN_CH];  // 32 KB (proj path)
  const int tid = threadIdx.x;

  if (blockIdx.x >= nblocksA) {
    // ---- scan1 path: 256 threads scan 1024 counts -> offsets + partial ----
    __shared__ int wsum[4];
    const int sb = blockIdx.x - nblocksA;
    const int base = sb * SCAN_ELEMS + tid * 4;
    const int n = nnodes;
    int v0 = (base + 0 < n) ? counts[base + 0] : 0;
    int v1 = (base + 1 < n) ? counts[base + 1] : 0;
    int v2 = (base + 2 < n) ? counts[base + 2] : 0;
    int v3 = (base + 3 < n) ? counts[base + 3] : 0;
    const int tsum = v0 + v1 + v2 + v3;
    const int lane = tid & 63;
    const int wid = tid >> 6;
    int incl = tsum;
#pragma unroll
    for (int d = 1; d < 64; d <<= 1) {
      int t = __shfl_up(incl, d, 64);
      if (lane >= d) incl += t;
    }
    if (lane == 63) wsum[wid] = incl;
    __syncthreads();
    int wexcl = incl - tsum;  // exclusive within wave
    int bexcl = 0;
#pragma unroll
    for (int wq = 0; wq < 4; ++wq) bexcl += (wq < wid) ? wsum[wq] : 0;
    const int te = bexcl + wexcl;
    if (base + 0 <= n) offsets[base + 0] = te;
    if (base + 1 <= n) offsets[base + 1] = te + v0;
    if (base + 2 <= n) offsets[base + 2] = te + v0 + v1;
    if (base + 3 <= n) offsets[base + 3] = te + v0 + v1 + v2;
    if (tid == 0) partials[sb] = wsum[0] + wsum[1] + wsum[2] + wsum[3];
    return;
  }

  // ---- proj path (R10 BM=64 form) ----
  const int wave = tid >> 6;
  const int lane = tid & 63;
  const int n0 = blockIdx.x * BM;

  {
    const int rsub = tid >> 6;
    const int cf = (tid & 63) * 4;
    const int cb = cf * 2;
#pragma unroll
    for (int it = 0; it < 16; ++it) {
      const int row_ = it * 4 + rsub;
      const int grow = n0 + row_;
      float4 xv = make_float4(0.f, 0.f, 0.f, 0.f);
      if (grow < nnodes) xv = *(const float4*)&x[(size_t)grow * N_IN_CH + cf];
      ushort4 b;
      b.x = f2bf(xv.x); b.y = f2bf(xv.y); b.z = f2bf(xv.z); b.w = f2bf(xv.w);
      const int cbs = cb ^ ((row_ & 7) << 4);
      *(ushort4*)((char*)at + row_ * 512 + cbs) = b;
    }
  }
  __syncthreads();

  f32x4 acc[4][4];
#pragma unroll
  for (int mt = 0; mt < 4; ++mt)
#pragma unroll
    for (int nt = 0; nt < 4; ++nt) acc[mt][nt] = (f32x4){0.f, 0.f, 0.f, 0.f};

  const int lmod = lane & 15;
  const int ldiv = lane >> 4;

  for (int ks = 0; ks < 8; ++ks) {
    bf16x8 a[4], b[4];
#pragma unroll
    for (int mt = 0; mt < 4; ++mt) {
      const int row_ = mt * 16 + lmod;
      const int kb = ks * 64 + ldiv * 16;
      const int cbs = kb ^ ((row_ & 7) << 4);
      a[mt] = *(const bf16x8*)((const char*)at + row_ * 512 + cbs);
    }
#pragma unroll
    for (int nt = 0; nt < 4; ++nt) {
      const int n = wave * 64 + nt * 16 + lmod;
      b[nt] = *(const bf16x8*)&bt[(size_t)n * N_IN_CH + ks * 32 + ldiv * 8];
    }
#pragma unroll
    for (int mt = 0; mt < 4; ++mt)
#pragma unroll
      for (int nt = 0; nt < 4; ++nt)
        acc[mt][nt] = __builtin_amdgcn_mfma_f32_16x16x32_bf16(
            a[mt], b[nt], acc[mt][nt], 0, 0, 0);
  }

  float atts[4], attd[4];
#pragma unroll
  for (int nt = 0; nt < 4; ++nt) {
    const int gcol = wave * 64 + nt * 16 + lmod;
    atts[nt] = att_src[gcol];
    attd[nt] = att_dst[gcol];
  }

#pragma unroll
  for (int mt = 0; mt < 4; ++mt) {
#pragma unroll
    for (int reg = 0; reg < 4; ++reg) {
      const int grow = n0 + mt * 16 + ldiv * 4 + reg;  // C/D: row=(lane>>4)*4+reg
      const bool ok = grow < nnodes;
      float vs = 0.f, vd = 0.f;
#pragma unroll
      for (int nt = 0; nt < 4; ++nt) {
        const float v = acc[mt][nt][reg];
        if (ok) xh[(size_t)grow * N_OUT + wave * 64 + nt * 16 + lmod] = f2h(v);
        vs = fmaf(v, atts[nt], vs);
        vd = fmaf(v, attd[nt], vd);
      }
#pragma unroll
      for (int d = 1; d < 16; d <<= 1) {
        vs += __shfl_xor(vs, d, 64);
        vd += __shfl_xor(vd, d, 64);
      }
      if (lmod == 0 && ok) {
        asrc[grow * HEADS + wave] = vs;
        adst[grow * HEADS + wave] = vd;
      }
    }
  }
}

// -- scatter: packed 16B edge record {col, 4xf16 weights}; inline scan2 ------
__global__ void scatter_kernel(const int* __restrict__ row, const int* __restrict__ col,
                               const int* __restrict__ rank,
                               const int* __restrict__ offsets,
                               const int* __restrict__ partials, int nparts,
                               const float* __restrict__ asrc,
                               const float* __restrict__ adst,
                               uint4* __restrict__ erec, int nedges) {
  const int lane = threadIdx.x & 63;
  const int excl = wave_scan_partials(partials, nparts, lane);
  int e = blockIdx.x * blockDim.x + threadIdx.x;
  if (e < nedges) {
    const int r = row[e];
    const int c = col[e];
    const int pos = offsets[r] + __shfl(excl, r >> 10, 64) + rank[e];
    const float4 s = *(const float4*)&asrc[r * 4];
    const float4 d = *(const float4*)&adst[c * 4];
    uint4 rec;
    rec.x = (uint)c;
    rec.y = (uint)f2h(__expf(lrelu(s.x + d.x))) |
            ((uint)f2h(__expf(lrelu(s.y + d.y))) << 16);
    rec.z = (uint)f2h(__expf(lrelu(s.z + d.z))) |
            ((uint)f2h(__expf(lrelu(s.w + d.w))) << 16);
    rec.w = 0u;
    erec[pos] = rec;
  }
}

// ------- gather: coalesced edge records + shuffle-addressed xh pipeline -----
__global__ __launch_bounds__(256) void gather_kernel(
    const int* __restrict__ offsets,
    const int* __restrict__ partials, int nparts,
    const uint4* __restrict__ erec,
    const ushort* __restrict__ xh, const float* __restrict__ bias,
    float* __restrict__ out, int nnodes) {
  __shared__ float pbuf[4][64 * 4];
  const int wv = threadIdx.x >> 6;
  const int lane = threadIdx.x & 63;
  const int n = blockIdx.x * 4 + wv;
  if (n >= nnodes) return;
  const int excl = wave_scan_partials(partials, nparts, lane);
  const int off = offsets[n] + __shfl(excl, n >> 10, 64);
  const int end = offsets[n + 1] + __shfl(excl, (n + 1) >> 10, 64);
  const int deg = end - off;
  const int half = lane >> 5;        // 0: even edges, 1: odd edges
  const int ch8 = (lane & 31) * 8;   // this lane's 8 output channels
  const int hh = (lane & 31) >> 3;   // head owning those channels

  float4 s4 = make_float4(0.f, 0.f, 0.f, 0.f);
  float a0 = 0.f, a1 = 0.f, a2 = 0.f, a3 = 0.f;
  float a4 = 0.f, a5 = 0.f, a6 = 0.f, a7 = 0.f;

  for (int b = 0; b < deg; b += 64) {
    const int cnt = min(64, deg - b);
    // one coalesced 16B load: source id + 4 precomputed f16 weights
    int cl_l = 0;
    float4 p = make_float4(0.f, 0.f, 0.f, 0.f);
    if (lane < cnt) {
      const uint4 rec = erec[off + b + lane];
      cl_l = (int)rec.x;
      p.x = h2f((ushort)(rec.y & 0xFFFFu));
      p.y = h2f((ushort)(rec.y >> 16));
      p.z = h2f((ushort)(rec.z & 0xFFFFu));
      p.w = h2f((ushort)(rec.z >> 16));
      s4.x += p.x; s4.y += p.y; s4.z += p.z; s4.w += p.w;
    }
    *(float4*)&pbuf[wv][lane * 4] = p;
    // same-wave LDS write->read ordered via lgkmcnt (no barrier needed)

    for (int j = 0; j < cnt; j += 16) {
      // distribute addresses via shuffles, issue payload loads immediately.
      // invalid tail slots carry cl=0 (safe read) and weight 0.
      int cq[8];
#pragma unroll
      for (int q = 0; q < 8; ++q) cq[q] = __shfl(cl_l, j + 2 * q + half, 64);
      uint4 xq[8];
#pragma unroll
      for (int q = 0; q < 8; ++q)
        xq[q] = *(const uint4*)&xh[(size_t)cq[q] * N_OUT + ch8];

      float wq[8];
#pragma unroll
      for (int q = 0; q < 8; ++q) wq[q] = pbuf[wv][(j + 2 * q + half) * 4 + hh];

#pragma unroll
      for (int q = 0; q < 8; ++q) {
        a0 = fmaf(wq[q], h2f((ushort)(xq[q].x & 0xFFFFu)), a0);
        a1 = fmaf(wq[q], h2f((ushort)(xq[q].x >> 16)), a1);
        a2 = fmaf(wq[q], h2f((ushort)(xq[q].y & 0xFFFFu)), a2);
        a3 = fmaf(wq[q], h2f((ushort)(xq[q].y >> 16)), a3);
        a4 = fmaf(wq[q], h2f((ushort)(xq[q].z & 0xFFFFu)), a4);
        a5 = fmaf(wq[q], h2f((ushort)(xq[q].z >> 16)), a5);
        a6 = fmaf(wq[q], h2f((ushort)(xq[q].w & 0xFFFFu)), a6);
        a7 = fmaf(wq[q], h2f((ushort)(xq[q].w >> 16)), a7);
      }
    }
  }

  // combine the two edge-halves (both halves end with the full sum)
  a0 += __shfl_xor(a0, 32, 64);
  a1 += __shfl_xor(a1, 32, 64);
  a2 += __shfl_xor(a2, 32, 64);
  a3 += __shfl_xor(a3, 32, 64);
  a4 += __shfl_xor(a4, 32, 64);
  a5 += __shfl_xor(a5, 32, 64);
  a6 += __shfl_xor(a6, 32, 64);
  a7 += __shfl_xor(a7, 32, 64);

  // reduce softmax denominators across all lanes
#pragma unroll
  for (int d = 1; d < 64; d <<= 1) {
    s4.x += __shfl_xor(s4.x, d, 64);
    s4.y += __shfl_xor(s4.y, d, 64);
    s4.z += __shfl_xor(s4.z, d, 64);
    s4.w += __shfl_xor(s4.w, d, 64);
  }
  const float sh = (hh == 0) ? s4.x : (hh == 1) ? s4.y : (hh == 2) ? s4.z : s4.w;
  const float invh = 1.f / fmaxf(sh, 1e-16f);

  // each half writes 4 of the lane's 8 channels (fully coalesced 256 floats)
  const int wch = ch8 + half * 4;
  const float4 b4 = *(const float4*)&bias[wch];
  float4 o;
  o.x = fmaf(half ? a4 : a0, invh, b4.x);
  o.y = fmaf(half ? a5 : a1, invh, b4.y);
  o.z = fmaf(half ? a6 : a2, invh, b4.z);
  o.w = fmaf(half ? a7 : a3, invh, b4.w);
  *(float4*)&out[(size_t)n * N_OUT + wch] = o;
}

extern "C" void kernel_launch(void* const* d_in, const int* in_sizes, int n_in,
                              void* d_out, int out_size, void* d_ws, size_t ws_size,
                              hipStream_t stream) {
  const float* x        = (const float*)d_in[0];
  const int*   edge_idx = (const int*)d_in[1];
  const float* weight   = (const float*)d_in[2];
  const float* att_src  = (const float*)d_in[3];
  const float* att_dst  = (const float*)d_in[4];
  const float* bias     = (const float*)d_in[5];
  float* out = (float*)d_out;

  const int nnodes = in_sizes[0] / N_IN_CH;
  const int nedges = in_sizes[1] / 2;
  const int* row = edge_idx;            // destinations (segment index)
  const int* col = edge_idx + nedges;   // sources (features gathered)

  char* wsb = (char*)d_ws;
  size_t woff = 0;
  auto alloc = [&](size_t bytes) -> char* {
    char* p = wsb + woff;
    woff += (bytes + 255) & ~(size_t)255;
    return p;
  };
  ushort* xh    = (ushort*)alloc((size_t)nnodes * N_OUT * sizeof(ushort));
  ushort* bt    = (ushort*)alloc((size_t)N_OUT * N_IN_CH * sizeof(ushort));
  float* asrc   = (float*)alloc((size_t)nnodes * HEADS * sizeof(float));
  float* adst   = (float*)alloc((size_t)nnodes * HEADS * sizeof(float));
  int* counts   = (int*)alloc((size_t)nnodes * sizeof(int));
  int* offsets  = (int*)alloc((size_t)(nnodes + 1) * sizeof(int));
  int* partials = (int*)alloc(256 * sizeof(int));
  int* rank     = (int*)alloc((size_t)nedges * sizeof(int));
  uint4* erec   = (uint4*)alloc((size_t)nedges * sizeof(uint4));

  convert_w<<<256, 256, 0, stream>>>(weight, bt, counts, nnodes);

  const int eblocks = (nedges + 255) / 256;
  count_kernel<<<eblocks, 256, 0, stream>>>(row, counts, rank, nedges);

  const int nblocksA = (nnodes + BM - 1) / BM;                     // 782
  const int nscan = (nnodes + 1 + SCAN_ELEMS - 1) / SCAN_ELEMS;    // 49
  proj_scan<<<nblocksA + nscan, 256, 0, stream>>>(
      x, bt, att_src, att_dst, xh, asrc, adst, nnodes, nblocksA,
      counts, offsets, partials);

  scatter_kernel<<<eblocks, 256, 0, stream>>>(row, col, rank, offsets,
                                              partials, nscan,
                                              asrc, adst, erec, nedges);

  gather_kernel<<<(nnodes + 3) / 4, 256, 0, stream>>>(offsets, partials, nscan,
                                                      erec, xh, bias, out, nnodes);
}

// Round 14
// 164.753 us; speedup vs baseline: 1.0261x; 1.0070x over previous
//
#include <hip/hip_runtime.h>
#include <hip/hip_fp16.h>
#include <math.h>

#define N_IN_CH 256
#define N_OUT   256   // HEADS * OUT_CH
#define HEADS   4
#define OUT_CH  64
#define BM      64    // rows per block (processed as 2 halves of 32)
#define HM      32    // half-tile rows
#define CPAD    16    // counts stride (ints) -> one counter per 64B line
#define SCAN_ELEMS 1024   // elements per scan block (256 threads x 4)

typedef __attribute__((ext_vector_type(8))) short bf16x8;
typedef __attribute__((ext_vector_type(4))) float f32x4;

__device__ __forceinline__ float lrelu(float a) {
  return a >= 0.f ? a : 0.2f * a;
}

__device__ __forceinline__ ushort f2bf(float f) {
  uint u = __float_as_uint(f);
  uint r = (u + 0x7FFFu + ((u >> 16) & 1u)) >> 16;
  return (ushort)r;
}

__device__ __forceinline__ ushort f2h(float f) {
  return __half_as_ushort(__float2half(f));
}
__device__ __forceinline__ float h2f(ushort u) {
  return __half2float(__ushort_as_half(u));
}

// wave-level exclusive scan of partials[0..nparts) -> per-lane excl value
__device__ __forceinline__ int wave_scan_partials(const int* __restrict__ partials,
                                                  int nparts, int lane) {
  int pv = (lane < nparts) ? partials[lane] : 0;
  int incl = pv;
#pragma unroll
  for (int d = 1; d < 64; d <<= 1) {
    int t = __shfl_up(incl, d, 64);
    if (lane >= d) incl += t;
  }
  return incl - pv;
}

// -------- Kernel W: weight [H][K][C] fp32 -> Bt [N][K] bf16; zero counts ----
__global__ void convert_w(const float* __restrict__ w, ushort* __restrict__ bt,
                          int* __restrict__ counts, int nnodes) {
  const int idx = blockIdx.x * 256 + threadIdx.x;  // 0..65535
  if (idx < nnodes) counts[idx * CPAD] = 0;
  const int n = idx >> 8, k = idx & 255;
  const int h = n >> 6, c = n & 63;
  bt[idx] = f2bf(w[h * (N_IN_CH * OUT_CH) + k * OUT_CH + c]);
}

// ------- Kernel B: count edges per destination + per-edge rank (1/thread) ---
// Counters padded to one per 64B line: un-padded, 16 counters/line x 16
// edges/counter = 256 serialized same-line atomics; padded = 16.
__global__ void count_kernel(const int* __restrict__ row, int* __restrict__ counts,
                             int* __restrict__ rank, int nedges) {
  int e = blockIdx.x * blockDim.x + threadIdx.x;
  if (e < nedges) rank[e] = atomicAdd(&counts[row[e] * CPAD], 1);
}

// ---- Kernel A: proj (blocks [0,nblocksA)) || scan1 (tail blocks) -----------
// proj processes its 64 rows as TWO sequential 32-row halves sharing one
// 16KB LDS buffer with acc[2][4] (32 AGPR): footprint ~2x smaller than the
// monolithic 32KB/64-AGPR version -> ~2x occupancy (was 24%, 2 blocks/CU).
__global__ __launch_bounds__(256) void proj_scan(
    const float* __restrict__ x, const ushort* __restrict__ bt,
    const float* __restrict__ att_src, const float* __restrict__ att_dst,
    ushort* __restrict__ xh, float* __restrict__ asrc, float* __restrict__ adst,
    int nnodes, int nblocksA,
    const int* __restrict__ counts, int* __restrict__ offsets,
    int* __restrict__ partials) {
  __shared__ ushort at[HM * N_IN_CH];  // 16 KB, XOR-swizzled rows (bf16)
  const int tid = threadIdx.x;

  if (blockIdx.x >= nblocksA) {
    // ---- scan1 path: 256 threads scan 1024 padded counts ----
    __shared__ int wsum[4];
    const int sb = blockIdx.x - nblocksA;
    const int base = sb * SCAN_ELEMS + tid * 4;
    const int n = nnodes;
    int v0 = (base + 0 < n) ? counts[(base + 0) * CPAD] : 0;
    int v1 = (base + 1 < n) ? counts[(base + 1) * CPAD] : 0;
    int v2 = (base + 2 < n) ? counts[(base + 2) * CPAD] : 0;
    int v3 = (base + 3 < n) ? counts[(base + 3) * CPAD] : 0;
    const int tsum = v0 + v1 + v2 + v3;
    const int lane = tid & 63;
    const int wid = tid >> 6;
    int incl = tsum;
#pragma unroll
    for (int d = 1; d < 64; d <<= 1) {
      int t = __shfl_up(incl, d, 64);
      if (lane >= d) incl += t;
    }
    if (lane == 63) wsum[wid] = incl;
    __syncthreads();
    int wexcl = incl - tsum;  // exclusive within wave
    int bexcl = 0;
#pragma unroll
    for (int wq = 0; wq < 4; ++wq) bexcl += (wq < wid) ? wsum[wq] : 0;
    const int te = bexcl + wexcl;
    if (base + 0 <= n) offsets[base + 0] = te;
    if (base + 1 <= n) offsets[base + 1] = te + v0;
    if (base + 2 <= n) offsets[base + 2] = te + v0 + v1;
    if (base + 3 <= n) offsets[base + 3] = te + v0 + v1 + v2;
    if (tid == 0) partials[sb] = wsum[0] + wsum[1] + wsum[2] + wsum[3];
    return;
  }

  // ---- proj path: two 32-row halves ----
  const int wave = tid >> 6;
  const int lane = tid & 63;
  const int lmod = lane & 15;
  const int ldiv = lane >> 4;

  float atts[4], attd[4];
#pragma unroll
  for (int nt = 0; nt < 4; ++nt) {
    const int gcol = wave * 64 + nt * 16 + lmod;
    atts[nt] = att_src[gcol];
    attd[nt] = att_dst[gcol];
  }

  for (int h0 = 0; h0 < 2; ++h0) {
    const int n0 = blockIdx.x * BM + h0 * HM;

    // stage 32 rows: fp32 -> bf16, swizzled LDS write (conflict-free)
    {
      const int rsub = tid >> 6;
      const int cf = (tid & 63) * 4;
      const int cb = cf * 2;
#pragma unroll
      for (int it = 0; it < 8; ++it) {
        const int lr = it * 4 + rsub;          // local row 0..31
        const int grow = n0 + lr;
        float4 xv = make_float4(0.f, 0.f, 0.f, 0.f);
        if (grow < nnodes) xv = *(const float4*)&x[(size_t)grow * N_IN_CH + cf];
        ushort4 b;
        b.x = f2bf(xv.x); b.y = f2bf(xv.y); b.z = f2bf(xv.z); b.w = f2bf(xv.w);
        const int cbs = cb ^ ((lr & 7) << 4);
        *(ushort4*)((char*)at + lr * 512 + cbs) = b;
      }
    }
    __syncthreads();

    f32x4 acc[2][4];
#pragma unroll
    for (int mt = 0; mt < 2; ++mt)
#pragma unroll
      for (int nt = 0; nt < 4; ++nt) acc[mt][nt] = (f32x4){0.f, 0.f, 0.f, 0.f};

    for (int ks = 0; ks < 8; ++ks) {
      bf16x8 a[2], b[4];
#pragma unroll
      for (int mt = 0; mt < 2; ++mt) {
        const int lr = mt * 16 + lmod;
        const int kb = ks * 64 + ldiv * 16;
        const int cbs = kb ^ ((lr & 7) << 4);
        a[mt] = *(const bf16x8*)((const char*)at + lr * 512 + cbs);
      }
#pragma unroll
      for (int nt = 0; nt < 4; ++nt) {
        const int n = wave * 64 + nt * 16 + lmod;
        b[nt] = *(const bf16x8*)&bt[(size_t)n * N_IN_CH + ks * 32 + ldiv * 8];
      }
#pragma unroll
      for (int mt = 0; mt < 2; ++mt)
#pragma unroll
        for (int nt = 0; nt < 4; ++nt)
          acc[mt][nt] = __builtin_amdgcn_mfma_f32_16x16x32_bf16(
              a[mt], b[nt], acc[mt][nt], 0, 0, 0);
    }

#pragma unroll
    for (int mt = 0; mt < 2; ++mt) {
#pragma unroll
      for (int reg = 0; reg < 4; ++reg) {
        const int grow = n0 + mt * 16 + ldiv * 4 + reg;  // C/D: row=(lane>>4)*4+reg
        const bool ok = grow < nnodes;
        float vs = 0.f, vd = 0.f;
#pragma unroll
        for (int nt = 0; nt < 4; ++nt) {
          const float v = acc[mt][nt][reg];
          if (ok) xh[(size_t)grow * N_OUT + wave * 64 + nt * 16 + lmod] = f2h(v);
          vs = fmaf(v, atts[nt], vs);
          vd = fmaf(v, attd[nt], vd);
        }
#pragma unroll
        for (int d = 1; d < 16; d <<= 1) {
          vs += __shfl_xor(vs, d, 64);
          vd += __shfl_xor(vd, d, 64);
        }
        if (lmod == 0 && ok) {
          asrc[grow * HEADS + wave] = vs;
          adst[grow * HEADS + wave] = vd;
        }
      }
    }
    __syncthreads();  // LDS reused by next half
  }
}

// -- scatter: packed 16B edge record {col, 4xf16 weights}; inline scan2 ------
__global__ void scatter_kernel(const int* __restrict__ row, const int* __restrict__ col,
                               const int* __restrict__ rank,
                               const int* __restrict__ offsets,
                               const int* __restrict__ partials, int nparts,
                               const float* __restrict__ asrc,
                               const float* __restrict__ adst,
                               uint4* __restrict__ erec, int nedges) {
  const int lane = threadIdx.x & 63;
  const int excl = wave_scan_partials(partials, nparts, lane);
  int e = blockIdx.x * blockDim.x + threadIdx.x;
  if (e < nedges) {
    const int r = row[e];
    const int c = col[e];
    const int pos = offsets[r] + __shfl(excl, r >> 10, 64) + rank[e];
    const float4 s = *(const float4*)&asrc[r * 4];
    const float4 d = *(const float4*)&adst[c * 4];
    uint4 rec;
    rec.x = (uint)c;
    rec.y = (uint)f2h(__expf(lrelu(s.x + d.x))) |
            ((uint)f2h(__expf(lrelu(s.y + d.y))) << 16);
    rec.z = (uint)f2h(__expf(lrelu(s.z + d.z))) |
            ((uint)f2h(__expf(lrelu(s.w + d.w))) << 16);
    rec.w = 0u;
    erec[pos] = rec;
  }
}

// ------- gather: coalesced edge records + shuffle-addressed xh pipeline -----
__global__ __launch_bounds__(256) void gather_kernel(
    const int* __restrict__ offsets,
    const int* __restrict__ partials, int nparts,
    const uint4* __restrict__ erec,
    const ushort* __restrict__ xh, const float* __restrict__ bias,
    float* __restrict__ out, int nnodes) {
  __shared__ float pbuf[4][64 * 4];
  const int wv = threadIdx.x >> 6;
  const int lane = threadIdx.x & 63;
  const int n = blockIdx.x * 4 + wv;
  if (n >= nnodes) return;
  const int excl = wave_scan_partials(partials, nparts, lane);
  const int off = offsets[n] + __shfl(excl, n >> 10, 64);
  const int end = offsets[n + 1] + __shfl(excl, (n + 1) >> 10, 64);
  const int deg = end - off;
  const int half = lane >> 5;        // 0: even edges, 1: odd edges
  const int ch8 = (lane & 31) * 8;   // this lane's 8 output channels
  const int hh = (lane & 31) >> 3;   // head owning those channels

  float4 s4 = make_float4(0.f, 0.f, 0.f, 0.f);
  float a0 = 0.f, a1 = 0.f, a2 = 0.f, a3 = 0.f;
  float a4 = 0.f, a5 = 0.f, a6 = 0.f, a7 = 0.f;

  for (int b = 0; b < deg; b += 64) {
    const int cnt = min(64, deg - b);
    // one coalesced 16B load: source id + 4 precomputed f16 weights
    int cl_l = 0;
    float4 p = make_float4(0.f, 0.f, 0.f, 0.f);
    if (lane < cnt) {
      const uint4 rec = erec[off + b + lane];
      cl_l = (int)rec.x;
      p.x = h2f((ushort)(rec.y & 0xFFFFu));
      p.y = h2f((ushort)(rec.y >> 16));
      p.z = h2f((ushort)(rec.z & 0xFFFFu));
      p.w = h2f((ushort)(rec.z >> 16));
      s4.x += p.x; s4.y += p.y; s4.z += p.z; s4.w += p.w;
    }
    *(float4*)&pbuf[wv][lane * 4] = p;
    // same-wave LDS write->read ordered via lgkmcnt (no barrier needed)

    for (int j = 0; j < cnt; j += 16) {
      // distribute addresses via shuffles, issue payload loads immediately.
      // invalid tail slots carry cl=0 (safe read) and weight 0.
      int cq[8];
#pragma unroll
      for (int q = 0; q < 8; ++q) cq[q] = __shfl(cl_l, j + 2 * q + half, 64);
      uint4 xq[8];
#pragma unroll
      for (int q = 0; q < 8; ++q)
        xq[q] = *(const uint4*)&xh[(size_t)cq[q] * N_OUT + ch8];

      float wq[8];
#pragma unroll
      for (int q = 0; q < 8; ++q) wq[q] = pbuf[wv][(j + 2 * q + half) * 4 + hh];

#pragma unroll
      for (int q = 0; q < 8; ++q) {
        a0 = fmaf(wq[q], h2f((ushort)(xq[q].x & 0xFFFFu)), a0);
        a1 = fmaf(wq[q], h2f((ushort)(xq[q].x >> 16)), a1);
        a2 = fmaf(wq[q], h2f((ushort)(xq[q].y & 0xFFFFu)), a2);
        a3 = fmaf(wq[q], h2f((ushort)(xq[q].y >> 16)), a3);
        a4 = fmaf(wq[q], h2f((ushort)(xq[q].z & 0xFFFFu)), a4);
        a5 = fmaf(wq[q], h2f((ushort)(xq[q].z >> 16)), a5);
        a6 = fmaf(wq[q], h2f((ushort)(xq[q].w & 0xFFFFu)), a6);
        a7 = fmaf(wq[q], h2f((ushort)(xq[q].w >> 16)), a7);
      }
    }
  }

  // combine the two edge-halves (both halves end with the full sum)
  a0 += __shfl_xor(a0, 32, 64);
  a1 += __shfl_xor(a1, 32, 64);
  a2 += __shfl_xor(a2, 32, 64);
  a3 += __shfl_xor(a3, 32, 64);
  a4 += __shfl_xor(a4, 32, 64);
  a5 += __shfl_xor(a5, 32, 64);
  a6 += __shfl_xor(a6, 32, 64);
  a7 += __shfl_xor(a7, 32, 64);

  // reduce softmax denominators across all lanes
#pragma unroll
  for (int d = 1; d < 64; d <<= 1) {
    s4.x += __shfl_xor(s4.x, d, 64);
    s4.y += __shfl_xor(s4.y, d, 64);
    s4.z += __shfl_xor(s4.z, d, 64);
    s4.w += __shfl_xor(s4.w, d, 64);
  }
  const float sh = (hh == 0) ? s4.x : (hh == 1) ? s4.y : (hh == 2) ? s4.z : s4.w;
  const float invh = 1.f / fmaxf(sh, 1e-16f);

  // each half writes 4 of the lane's 8 channels (fully coalesced 256 floats)
  const int wch = ch8 + half * 4;
  const float4 b4 = *(const float4*)&bias[wch];
  float4 o;
  o.x = fmaf(half ? a4 : a0, invh, b4.x);
  o.y = fmaf(half ? a5 : a1, invh, b4.y);
  o.z = fmaf(half ? a6 : a2, invh, b4.z);
  o.w = fmaf(half ? a7 : a3, invh, b4.w);
  *(float4*)&out[(size_t)n * N_OUT + wch] = o;
}

extern "C" void kernel_launch(void* const* d_in, const int* in_sizes, int n_in,
                              void* d_out, int out_size, void* d_ws, size_t ws_size,
                              hipStream_t stream) {
  const float* x        = (const float*)d_in[0];
  const int*   edge_idx = (const int*)d_in[1];
  const float* weight   = (const float*)d_in[2];
  const float* att_src  = (const float*)d_in[3];
  const float* att_dst  = (const float*)d_in[4];
  const float* bias     = (const float*)d_in[5];
  float* out = (float*)d_out;

  const int nnodes = in_sizes[0] / N_IN_CH;
  const int nedges = in_sizes[1] / 2;
  const int* row = edge_idx;            // destinations (segment index)
  const int* col = edge_idx + nedges;   // sources (features gathered)

  char* wsb = (char*)d_ws;
  size_t woff = 0;
  auto alloc = [&](size_t bytes) -> char* {
    char* p = wsb + woff;
    woff += (bytes + 255) & ~(size_t)255;
    return p;
  };
  ushort* xh    = (ushort*)alloc((size_t)nnodes * N_OUT * sizeof(ushort));
  ushort* bt    = (ushort*)alloc((size_t)N_OUT * N_IN_CH * sizeof(ushort));
  float* asrc   = (float*)alloc((size_t)nnodes * HEADS * sizeof(float));
  float* adst   = (float*)alloc((size_t)nnodes * HEADS * sizeof(float));
  int* counts   = (int*)alloc((size_t)nnodes * CPAD * sizeof(int));
  int* offsets  = (int*)alloc((size_t)(nnodes + 1) * sizeof(int));
  int* partials = (int*)alloc(256 * sizeof(int));
  int* rank     = (int*)alloc((size_t)nedges * sizeof(int));
  uint4* erec   = (uint4*)alloc((size_t)nedges * sizeof(uint4));

  convert_w<<<256, 256, 0, stream>>>(weight, bt, counts, nnodes);

  const int eblocks = (nedges + 255) / 256;
  count_kernel<<<eblocks, 256, 0, stream>>>(row, counts, rank, nedges);

  const int nblocksA = (nnodes + BM - 1) / BM;                     // 782
  const int nscan = (nnodes + 1 + SCAN_ELEMS - 1) / SCAN_ELEMS;    // 49
  proj_scan<<<nblocksA + nscan, 256, 0, stream>>>(
      x, bt, att_src, att_dst, xh, asrc, adst, nnodes, nblocksA,
      counts, offsets, partials);

  scatter_kernel<<<eblocks, 256, 0, stream>>>(row, col, rank, offsets,
                                              partials, nscan,
                                              asrc, adst, erec, nedges);

  gather_kernel<<<(nnodes + 3) / 4, 256, 0, stream>>>(offsets, partials, nscan,
                                                      erec, xh, bias, out, nnodes);
}

// Round 15
// 150.139 us; speedup vs baseline: 1.1260x; 1.0973x over previous
//
#include <hip/hip_runtime.h>
#include <hip/hip_fp16.h>
#include <math.h>

#define N_IN_CH 256
#define N_OUT   256   // HEADS * OUT_CH
#define HEADS   4
#define OUT_CH  64
#define BM      64    // rows per proj block (two halves of HM)
#define HM      32    // half-tile rows -> 16KB LDS, 32 AGPR
#define SCAN_BLOCK 1024

typedef __attribute__((ext_vector_type(8))) short bf16x8;
typedef __attribute__((ext_vector_type(4))) float f32x4;

__device__ __forceinline__ float lrelu(float a) {
  return a >= 0.f ? a : 0.2f * a;
}

__device__ __forceinline__ ushort f2bf(float f) {
  uint u = __float_as_uint(f);
  uint r = (u + 0x7FFFu + ((u >> 16) & 1u)) >> 16;
  return (ushort)r;
}

__device__ __forceinline__ ushort f2h(float f) {
  return __half_as_ushort(__float2half(f));
}
__device__ __forceinline__ float h2f(ushort u) {
  return __half2float(__ushort_as_half(u));
}

// wave-level exclusive scan of partials[0..nparts) -> per-lane excl value
__device__ __forceinline__ int wave_scan_partials(const int* __restrict__ partials,
                                                  int nparts, int lane) {
  int pv = (lane < nparts) ? partials[lane] : 0;
  int incl = pv;
#pragma unroll
  for (int d = 1; d < 64; d <<= 1) {
    int t = __shfl_up(incl, d, 64);
    if (lane >= d) incl += t;
  }
  return incl - pv;
}

// -------- Kernel W: weight [H][K][C] fp32 -> Bt [N][K] bf16; zero counts ----
__global__ void convert_w(const float* __restrict__ w, ushort* __restrict__ bt,
                          int* __restrict__ counts, int nnodes) {
  const int idx = blockIdx.x * 256 + threadIdx.x;  // 0..65535
  if (idx < nnodes) counts[idx] = 0;
  const int n = idx >> 8, k = idx & 255;
  const int h = n >> 6, c = n & 63;
  bt[idx] = f2bf(w[h * (N_IN_CH * OUT_CH) + k * OUT_CH + c]);
}

// ---- Kernel A: INTERLEAVED heterogeneous proj || count ---------------------
// Ledger audit (R10-R14): count+proj cost 84-90us separate, 81us hetero-fused
// (R11) -- fusion was the best config, limited only by 2 blocks/CU occupancy
// (proj-then-count queuing). Fix: (a) two-half proj -> 16KB LDS + 32 AGPR =
// ~7 blocks/CU; (b) every-5th-block interleave so each CU co-resides proj and
// count blocks from the start: atomics hide under MFMA stalls and vice versa.
__global__ __launch_bounds__(256) void proj_count(
    const float* __restrict__ x, const ushort* __restrict__ bt,
    const float* __restrict__ att_src, const float* __restrict__ att_dst,
    ushort* __restrict__ xh, float* __restrict__ asrc, float* __restrict__ adst,
    int nnodes, int nblocksA,
    const int* __restrict__ row, int* __restrict__ counts,
    int* __restrict__ rank, int nedges) {
  __shared__ ushort at[HM * N_IN_CH];  // 16 KB (proj path only)
  const int tid = threadIdx.x;
  const int bid = blockIdx.x;
  const int g = bid / 5;
  const bool is_proj = (bid % 5 == 0) && (g < nblocksA);

  if (!is_proj) {  // ---- count path: 4k + (bid%5) - 1, bijective 0..eblk-1 --
    const int cb = (bid % 5 == 0) ? (4 * g)  // only when g >= nblocksA (tail)
                                  : (4 * g + (bid % 5) - 1);
    const int e = cb * 256 + tid;
    if (e < nedges) rank[e] = atomicAdd(&counts[row[e]], 1);
    return;
  }

  // ---- proj path: two 32-row halves sharing the 16KB LDS buffer ----
  const int wave = tid >> 6;
  const int lane = tid & 63;
  const int lmod = lane & 15;
  const int ldiv = lane >> 4;

  float atts[4], attd[4];
#pragma unroll
  for (int nt = 0; nt < 4; ++nt) {
    const int gcol = wave * 64 + nt * 16 + lmod;
    atts[nt] = att_src[gcol];
    attd[nt] = att_dst[gcol];
  }

  for (int h0 = 0; h0 < 2; ++h0) {
    const int n0 = g * BM + h0 * HM;

    {
      const int rsub = tid >> 6;
      const int cf = (tid & 63) * 4;
      const int cb2 = cf * 2;
#pragma unroll
      for (int it = 0; it < 8; ++it) {
        const int lr = it * 4 + rsub;          // local row 0..31
        const int grow = n0 + lr;
        float4 xv = make_float4(0.f, 0.f, 0.f, 0.f);
        if (grow < nnodes) xv = *(const float4*)&x[(size_t)grow * N_IN_CH + cf];
        ushort4 b;
        b.x = f2bf(xv.x); b.y = f2bf(xv.y); b.z = f2bf(xv.z); b.w = f2bf(xv.w);
        const int cbs = cb2 ^ ((lr & 7) << 4);
        *(ushort4*)((char*)at + lr * 512 + cbs) = b;
      }
    }
    __syncthreads();

    f32x4 acc[2][4];
#pragma unroll
    for (int mt = 0; mt < 2; ++mt)
#pragma unroll
      for (int nt = 0; nt < 4; ++nt) acc[mt][nt] = (f32x4){0.f, 0.f, 0.f, 0.f};

    for (int ks = 0; ks < 8; ++ks) {
      bf16x8 a[2], b[4];
#pragma unroll
      for (int mt = 0; mt < 2; ++mt) {
        const int lr = mt * 16 + lmod;
        const int kb = ks * 64 + ldiv * 16;
        const int cbs = kb ^ ((lr & 7) << 4);
        a[mt] = *(const bf16x8*)((const char*)at + lr * 512 + cbs);
      }
#pragma unroll
      for (int nt = 0; nt < 4; ++nt) {
        const int n = wave * 64 + nt * 16 + lmod;
        b[nt] = *(const bf16x8*)&bt[(size_t)n * N_IN_CH + ks * 32 + ldiv * 8];
      }
#pragma unroll
      for (int mt = 0; mt < 2; ++mt)
#pragma unroll
        for (int nt = 0; nt < 4; ++nt)
          acc[mt][nt] = __builtin_amdgcn_mfma_f32_16x16x32_bf16(
              a[mt], b[nt], acc[mt][nt], 0, 0, 0);
    }

#pragma unroll
    for (int mt = 0; mt < 2; ++mt) {
#pragma unroll
      for (int reg = 0; reg < 4; ++reg) {
        const int grow = n0 + mt * 16 + ldiv * 4 + reg;  // C/D row=(lane>>4)*4+reg
        const bool ok = grow < nnodes;
        float vs = 0.f, vd = 0.f;
#pragma unroll
        for (int nt = 0; nt < 4; ++nt) {
          const float v = acc[mt][nt][reg];
          if (ok) xh[(size_t)grow * N_OUT + wave * 64 + nt * 16 + lmod] = f2h(v);
          vs = fmaf(v, atts[nt], vs);
          vd = fmaf(v, attd[nt], vd);
        }
#pragma unroll
        for (int d = 1; d < 16; d <<= 1) {
          vs += __shfl_xor(vs, d, 64);
          vd += __shfl_xor(vd, d, 64);
        }
        if (lmod == 0 && ok) {
          asrc[grow * HEADS + wave] = vs;
          adst[grow * HEADS + wave] = vd;
        }
      }
    }
    __syncthreads();  // LDS reused by next half
  }
}

// ---------------- scan1: block-local exclusive scan over n+1 elems ----------
__global__ __launch_bounds__(SCAN_BLOCK) void scan1_kernel(
    const int* __restrict__ counts, int* __restrict__ offsets,
    int* __restrict__ partials, int n) {
  __shared__ int wsum[16];
  const int tid = threadIdx.x;
  const int lane = tid & 63;
  const int wid = tid >> 6;
  const int i = blockIdx.x * SCAN_BLOCK + tid;
  int v = (i < n) ? counts[i] : 0;
  int incl = v;
#pragma unroll
  for (int d = 1; d < 64; d <<= 1) {
    int t = __shfl_up(incl, d, 64);
    if (lane >= d) incl += t;
  }
  if (lane == 63) wsum[wid] = incl;
  __syncthreads();
  if (wid == 0) {
    int wv = (lane < 16) ? wsum[lane] : 0;
#pragma unroll
    for (int d = 1; d < 16; d <<= 1) {
      int t = __shfl_up(wv, d, 64);
      if (lane >= d) wv += t;
    }
    if (lane < 16) wsum[lane] = wv;
  }
  __syncthreads();
  const int wexcl = (wid == 0) ? 0 : wsum[wid - 1];
  if (i <= n) offsets[i] = wexcl + incl - v;
  if (tid == SCAN_BLOCK - 1) partials[blockIdx.x] = wsum[15];
}

// -- scatter: packed 16B edge record {col, 4xf16 weights}; inline scan2 ------
__global__ void scatter_kernel(const int* __restrict__ row, const int* __restrict__ col,
                               const int* __restrict__ rank,
                               const int* __restrict__ offsets,
                               const int* __restrict__ partials, int nparts,
                               const float* __restrict__ asrc,
                               const float* __restrict__ adst,
                               uint4* __restrict__ erec, int nedges) {
  const int lane = threadIdx.x & 63;
  const int excl = wave_scan_partials(partials, nparts, lane);
  int e = blockIdx.x * blockDim.x + threadIdx.x;
  if (e < nedges) {
    const int r = row[e];
    const int c = col[e];
    const int pos = offsets[r] + __shfl(excl, r >> 10, 64) + rank[e];
    const float4 s = *(const float4*)&asrc[r * 4];
    const float4 d = *(const float4*)&adst[c * 4];
    uint4 rec;
    rec.x = (uint)c;
    rec.y = (uint)f2h(__expf(lrelu(s.x + d.x))) |
            ((uint)f2h(__expf(lrelu(s.y + d.y))) << 16);
    rec.z = (uint)f2h(__expf(lrelu(s.z + d.z))) |
            ((uint)f2h(__expf(lrelu(s.w + d.w))) << 16);
    rec.w = 0u;
    erec[pos] = rec;
  }
}

// ------- gather: coalesced edge records + shuffle-addressed xh pipeline -----
__global__ __launch_bounds__(256) void gather_kernel(
    const int* __restrict__ offsets,
    const int* __restrict__ partials, int nparts,
    const uint4* __restrict__ erec,
    const ushort* __restrict__ xh, const float* __restrict__ bias,
    float* __restrict__ out, int nnodes) {
  __shared__ float pbuf[4][64 * 4];
  const int wv = threadIdx.x >> 6;
  const int lane = threadIdx.x & 63;
  const int n = blockIdx.x * 4 + wv;
  if (n >= nnodes) return;
  const int excl = wave_scan_partials(partials, nparts, lane);
  const int off = offsets[n] + __shfl(excl, n >> 10, 64);
  const int end = offsets[n + 1] + __shfl(excl, (n + 1) >> 10, 64);
  const int deg = end - off;
  const int half = lane >> 5;        // 0: even edges, 1: odd edges
  const int ch8 = (lane & 31) * 8;   // this lane's 8 output channels
  const int hh = (lane & 31) >> 3;   // head owning those channels

  float4 s4 = make_float4(0.f, 0.f, 0.f, 0.f);
  float a0 = 0.f, a1 = 0.f, a2 = 0.f, a3 = 0.f;
  float a4 = 0.f, a5 = 0.f, a6 = 0.f, a7 = 0.f;

  for (int b = 0; b < deg; b += 64) {
    const int cnt = min(64, deg - b);
    // one coalesced 16B load: source id + 4 precomputed f16 weights
    int cl_l = 0;
    float4 p = make_float4(0.f, 0.f, 0.f, 0.f);
    if (lane < cnt) {
      const uint4 rec = erec[off + b + lane];
      cl_l = (int)rec.x;
      p.x = h2f((ushort)(rec.y & 0xFFFFu));
      p.y = h2f((ushort)(rec.y >> 16));
      p.z = h2f((ushort)(rec.z & 0xFFFFu));
      p.w = h2f((ushort)(rec.z >> 16));
      s4.x += p.x; s4.y += p.y; s4.z += p.z; s4.w += p.w;
    }
    *(float4*)&pbuf[wv][lane * 4] = p;
    // same-wave LDS write->read ordered via lgkmcnt (no barrier needed)

    for (int j = 0; j < cnt; j += 16) {
      // distribute addresses via shuffles, issue payload loads immediately.
      // invalid tail slots carry cl=0 (safe read) and weight 0.
      int cq[8];
#pragma unroll
      for (int q = 0; q < 8; ++q) cq[q] = __shfl(cl_l, j + 2 * q + half, 64);
      uint4 xq[8];
#pragma unroll
      for (int q = 0; q < 8; ++q)
        xq[q] = *(const uint4*)&xh[(size_t)cq[q] * N_OUT + ch8];

      float wq[8];
#pragma unroll
      for (int q = 0; q < 8; ++q) wq[q] = pbuf[wv][(j + 2 * q + half) * 4 + hh];

#pragma unroll
      for (int q = 0; q < 8; ++q) {
        a0 = fmaf(wq[q], h2f((ushort)(xq[q].x & 0xFFFFu)), a0);
        a1 = fmaf(wq[q], h2f((ushort)(xq[q].x >> 16)), a1);
        a2 = fmaf(wq[q], h2f((ushort)(xq[q].y & 0xFFFFu)), a2);
        a3 = fmaf(wq[q], h2f((ushort)(xq[q].y >> 16)), a3);
        a4 = fmaf(wq[q], h2f((ushort)(xq[q].z & 0xFFFFu)), a4);
        a5 = fmaf(wq[q], h2f((ushort)(xq[q].z >> 16)), a5);
        a6 = fmaf(wq[q], h2f((ushort)(xq[q].w & 0xFFFFu)), a6);
        a7 = fmaf(wq[q], h2f((ushort)(xq[q].w >> 16)), a7);
      }
    }
  }

  // combine the two edge-halves (both halves end with the full sum)
  a0 += __shfl_xor(a0, 32, 64);
  a1 += __shfl_xor(a1, 32, 64);
  a2 += __shfl_xor(a2, 32, 64);
  a3 += __shfl_xor(a3, 32, 64);
  a4 += __shfl_xor(a4, 32, 64);
  a5 += __shfl_xor(a5, 32, 64);
  a6 += __shfl_xor(a6, 32, 64);
  a7 += __shfl_xor(a7, 32, 64);

  // reduce softmax denominators across all lanes
#pragma unroll
  for (int d = 1; d < 64; d <<= 1) {
    s4.x += __shfl_xor(s4.x, d, 64);
    s4.y += __shfl_xor(s4.y, d, 64);
    s4.z += __shfl_xor(s4.z, d, 64);
    s4.w += __shfl_xor(s4.w, d, 64);
  }
  const float sh = (hh == 0) ? s4.x : (hh == 1) ? s4.y : (hh == 2) ? s4.z : s4.w;
  const float invh = 1.f / fmaxf(sh, 1e-16f);

  // each half writes 4 of the lane's 8 channels (fully coalesced 256 floats)
  const int wch = ch8 + half * 4;
  const float4 b4 = *(const float4*)&bias[wch];
  float4 o;
  o.x = fmaf(half ? a4 : a0, invh, b4.x);
  o.y = fmaf(half ? a5 : a1, invh, b4.y);
  o.z = fmaf(half ? a6 : a2, invh, b4.z);
  o.w = fmaf(half ? a7 : a3, invh, b4.w);
  *(float4*)&out[(size_t)n * N_OUT + wch] = o;
}

extern "C" void kernel_launch(void* const* d_in, const int* in_sizes, int n_in,
                              void* d_out, int out_size, void* d_ws, size_t ws_size,
                              hipStream_t stream) {
  const float* x        = (const float*)d_in[0];
  const int*   edge_idx = (const int*)d_in[1];
  const float* weight   = (const float*)d_in[2];
  const float* att_src  = (const float*)d_in[3];
  const float* att_dst  = (const float*)d_in[4];
  const float* bias     = (const float*)d_in[5];
  float* out = (float*)d_out;

  const int nnodes = in_sizes[0] / N_IN_CH;
  const int nedges = in_sizes[1] / 2;
  const int* row = edge_idx;            // destinations (segment index)
  const int* col = edge_idx + nedges;   // sources (features gathered)

  char* wsb = (char*)d_ws;
  size_t woff = 0;
  auto alloc = [&](size_t bytes) -> char* {
    char* p = wsb + woff;
    woff += (bytes + 255) & ~(size_t)255;
    return p;
  };
  ushort* xh    = (ushort*)alloc((size_t)nnodes * N_OUT * sizeof(ushort));
  ushort* bt    = (ushort*)alloc((size_t)N_OUT * N_IN_CH * sizeof(ushort));
  float* asrc   = (float*)alloc((size_t)nnodes * HEADS * sizeof(float));
  float* adst   = (float*)alloc((size_t)nnodes * HEADS * sizeof(float));
  int* counts   = (int*)alloc((size_t)nnodes * sizeof(int));
  int* offsets  = (int*)alloc((size_t)(nnodes + 1) * sizeof(int));
  int* partials = (int*)alloc(256 * sizeof(int));
  int* rank     = (int*)alloc((size_t)nedges * sizeof(int));
  uint4* erec   = (uint4*)alloc((size_t)nedges * sizeof(uint4));

  convert_w<<<256, 256, 0, stream>>>(weight, bt, counts, nnodes);

  const int eblocks = (nedges + 255) / 256;                        // 3125
  const int nblocksA = (nnodes + BM - 1) / BM;                     // 782
  const int total = nblocksA + eblocks;                            // 3907
  proj_count<<<total, 256, 0, stream>>>(
      x, bt, att_src, att_dst, xh, asrc, adst, nnodes, nblocksA,
      row, counts, rank, nedges);

  const int nscan = (nnodes + 1 + SCAN_BLOCK - 1) / SCAN_BLOCK;    // 49
  scan1_kernel<<<nscan, SCAN_BLOCK, 0, stream>>>(counts, offsets, partials, nnodes);

  scatter_kernel<<<eblocks, 256, 0, stream>>>(row, col, rank, offsets,
                                              partials, nscan,
                                              asrc, adst, erec, nedges);

  gather_kernel<<<(nnodes + 3) / 4, 256, 0, stream>>>(offsets, partials, nscan,
                                                      erec, xh, bias, out, nnodes);
}